// Round 18
// baseline (1225.255 us; speedup 1.0000x reference)
//
#include <hip/hip_runtime.h>

#define BB 256      // batch
#define TT 2048     // timesteps
#define DD 32       // obs dim
#define HH 64       // hidden
#define GG 256      // 4*H gates
#define OB 8        // steps per output burst
#define LOG2E 1.44269504088896f

typedef float f32x4 __attribute__((ext_vector_type(4)));

// sigmoid with pre-scaled argument y = log2(e)*x: rcp(1 + 2^-y)
__device__ __forceinline__ float sig_e2(float y) {
    return __builtin_amdgcn_rcpf(1.0f + __builtin_exp2f(-y));
}
__device__ __forceinline__ float rdlane(float v, int k) {
    return __uint_as_float(__builtin_amdgcn_readlane(__float_as_uint(v), k));
}
// LDS-only barrier: drain lgkmcnt, leave global loads/stores in flight.
__device__ __forceinline__ void lds_barrier() {
    asm volatile("s_waitcnt lgkmcnt(0)" ::: "memory");
    __builtin_amdgcn_s_barrier();
    asm volatile("" ::: "memory");
}

// 8-WAY K-SPLIT, 512 threads/block, 256 blocks (one element per block,
// 2 waves per SIMD). Wave wv computes, for ALL 4 gates of unit l, the
// partial pre-activation over its K-slice (x[4wv..4wv+4), h[8wv..8wv+8)).
// Per-wave issue is ~halved vs the 4-wave split; the co-resident wave on
// each SIMD fills latency stalls (R15 showed 2 waves/SIMD cuts per-element
// step ~1213->~825 cyc; this keeps all 256 CUs busy while doing it).
// Exchange = 1 ds_write_b128 + 8 ds_read_b128; activations ILP-parallel
// post-read; h/c in-register replicas; weights pre-scaled by log2(e).
__global__ __launch_bounds__(512, 1) void lstm_k8_kernel(
    const float* __restrict__ y,    // [B, T, D]
    const float* __restrict__ Wx,   // [D, 4H]
    const float* __restrict__ Wh,   // [H, 4H]
    const float* __restrict__ b,    // [4H]
    float* __restrict__ out)        // [B, T, H]
{
    const int tid = threadIdx.x;      // 0..511
    const int wv  = tid >> 6;         // wave 0..7 = K-slice
    const int l   = tid & 63;         // lane = hidden unit
    const int batch = blockIdx.x;
    const int kb  = 8 * wv;           // h K-slice base

    __shared__ f32x4 gbuf[2][8][HH];      // [buf][wave][unit] partials (16 KB)
    __shared__ float obuf[2][OB][HH];     // output staging ring (4 KB)

    // ---- per-lane weight slices (coalesced; pre-scaled by log2e)
    float wh[4][8];                   // Wh rows kb..kb+7, cols g*64+l
#pragma unroll
    for (int g = 0; g < 4; ++g)
#pragma unroll
        for (int k = 0; k < 8; ++k)
            wh[g][k] = Wh[(kb + k) * GG + g * HH + l] * LOG2E;
    float wx4[4][4];                  // Wx rows 4wv..4wv+3, cols g*64+l
#pragma unroll
    for (int g = 0; g < 4; ++g)
#pragma unroll
        for (int d = 0; d < 4; ++d)
            wx4[g][d] = Wx[(4 * wv + d) * GG + g * HH + l] * LOG2E;
    float bj[4];                      // bias: only wave 0 carries it
#pragma unroll
    for (int g = 0; g < 4; ++g) bj[g] = (wv == 0) ? b[g * HH + l] * LOG2E : 0.0f;

    float c = 0.0f, h = 0.0f;         // lane l's replica of c[l], h[l]

    const float* ybase = y + (size_t)batch * (TT * DD) + 4 * wv;
    float* obase = out + (size_t)batch * (TT * HH);

    // x slice (4 floats) double-buffered; accumulators carried across steps
    float4 xa, xb;
    float a0[4], a1[4];
    {
        // a <- bias + x(0)*Wx ; xa <- x(1)
        const float4 x0 = *(const float4*)ybase;
#pragma unroll
        for (int g = 0; g < 4; ++g) {
            a0[g] = fmaf(x0.y, wx4[g][1], fmaf(x0.x, wx4[g][0], bj[g]));
            a1[g] = fmaf(x0.w, wx4[g][3], x0.z * wx4[g][2]);
        }
        xa = *(const float4*)(ybase + DD);
    }
    __syncthreads();   // once at init

    // XC: x(TI+1) regs (consumed in shadows); XN: prefetch target x(TI+2).
#define STEP(XC, XN, BUFI, TI, TL)                                            \
    {                                                                         \
        /* 1. chain head: h-GEMV, 8 rdlane each feeding 4 gates */            \
        _Pragma("unroll")                                                     \
        for (int k = 0; k < 4; ++k) {                                         \
            const float hk = rdlane(h, kb + k);                               \
            _Pragma("unroll")                                                 \
            for (int g = 0; g < 4; ++g) a0[g] = fmaf(hk, wh[g][k], a0[g]);    \
        }                                                                     \
        _Pragma("unroll")                                                     \
        for (int k = 4; k < 8; ++k) {                                         \
            const float hk = rdlane(h, kb + k);                               \
            _Pragma("unroll")                                                 \
            for (int g = 0; g < 4; ++g) a1[g] = fmaf(hk, wh[g][k], a1[g]);    \
        }                                                                     \
        /* 2. fold + publish partials (single b128 write) */                  \
        f32x4 pw;                                                             \
        pw.x = a0[0] + a1[0]; pw.y = a0[1] + a1[1];                           \
        pw.z = a0[2] + a1[2]; pw.w = a0[3] + a1[3];                           \
        gbuf[BUFI][wv][l] = pw;                                               \
        /* 3. shadow-a (covers write-ack): acc re-init + x d0,d1 + prefetch */\
        _Pragma("unroll")                                                     \
        for (int g = 0; g < 4; ++g)                                           \
            a0[g] = fmaf(XC.y, wx4[g][1], fmaf(XC.x, wx4[g][0], bj[g]));      \
        {                                                                     \
            const int tn_ = ((TI) + 2 < TT) ? ((TI) + 2) : (TT - 1);          \
            XN = *(const float4*)(ybase + (size_t)tn_ * DD);                  \
        }                                                                     \
        lds_barrier();                                                        \
        /* 4. reads issue; shadow-b (x d2,d3) fills their latency */          \
        const f32x4 P0 = gbuf[BUFI][0][l];                                    \
        const f32x4 P1 = gbuf[BUFI][1][l];                                    \
        const f32x4 P2 = gbuf[BUFI][2][l];                                    \
        const f32x4 P3 = gbuf[BUFI][3][l];                                    \
        const f32x4 P4 = gbuf[BUFI][4][l];                                    \
        const f32x4 P5 = gbuf[BUFI][5][l];                                    \
        const f32x4 P6 = gbuf[BUFI][6][l];                                    \
        const f32x4 P7 = gbuf[BUFI][7][l];                                    \
        _Pragma("unroll")                                                     \
        for (int g = 0; g < 4; ++g)                                           \
            a1[g] = fmaf(XC.w, wx4[g][3], XC.z * wx4[g][2]);                  \
        /* 5. sum partials; 4 activation chains ILP-parallel (log2e scale) */ \
        const f32x4 PS = ((P0 + P1) + (P2 + P3)) + ((P4 + P5) + (P6 + P7));   \
        const float i_ = sig_e2(PS.x);                                        \
        const float f_ = sig_e2(PS.y);                                        \
        const float g_ = fmaf(2.0f, sig_e2(2.0f * PS.z), -1.0f);  /* tanh */  \
        const float o_ = sig_e2(PS.w);                                        \
        c = fmaf(f_, c, i_ * g_);                                             \
        h = o_ * fmaf(2.0f, __builtin_amdgcn_rcpf(                            \
                1.0f + __builtin_exp2f(c * (-2.0f * LOG2E))), -1.0f);         \
        if (wv == 0) obuf[obi][TL][l] = h;                                    \
    }

    for (int t0 = 0; t0 < TT; t0 += OB) {
        const int obi = (t0 >> 3) & 1;
#pragma unroll
        for (int tp = 0; tp < OB; tp += 2) {
            STEP(xa, xb, 0, t0 + tp, tp)
            STEP(xb, xa, 1, t0 + tp + 1, tp + 1)
        }
        // publish wave-0's obuf rows, then coalesced burst store
        lds_barrier();
        {
            const int r  = tid >> 6;           // row 0..7
            const int ci = tid & 63;           // col 0..63
            obase[(size_t)(t0 + r) * HH + ci] = obuf[obi][r][ci];
        }
    }
#undef STEP
}

extern "C" void kernel_launch(void* const* d_in, const int* in_sizes, int n_in,
                              void* d_out, int out_size, void* d_ws, size_t ws_size,
                              hipStream_t stream) {
    const float* y  = (const float*)d_in[0];
    const float* Wx = (const float*)d_in[1];
    const float* Wh = (const float*)d_in[2];
    const float* b  = (const float*)d_in[3];
    float* out = (float*)d_out;

    lstm_k8_kernel<<<BB, 512, 0, stream>>>(y, Wx, Wh, b, out);
}